// Round 1
// baseline (2800.562 us; speedup 1.0000x reference)
//
#include <hip/hip_runtime.h>

#define DIM    512
#define KCODES 8192
#define NROWS  16384
#define BN 64
#define BC 64
#define BD 64

// ---------------- kernel 0: squared norms (one wave per row) ----------------
__global__ __launch_bounds__(256) void sqnorm_kernel(
    const float* __restrict__ x, const float* __restrict__ embed,
    float* __restrict__ e_sq, float* __restrict__ f_sq)
{
    int wave = blockIdx.x * 4 + (threadIdx.x >> 6);
    int lane = threadIdx.x & 63;
    const float* src;
    float* dst;
    if (wave < KCODES) {
        src = embed + (size_t)wave * DIM;
        dst = e_sq + wave;
    } else {
        int r = wave - KCODES;
        src = x + (size_t)r * DIM;
        dst = f_sq + r;
    }
    const float4* s4 = (const float4*)src;
    float4 a = s4[lane];
    float4 b = s4[lane + 64];
    float sum = a.x*a.x + a.y*a.y + a.z*a.z + a.w*a.w
              + b.x*b.x + b.y*b.y + b.z*b.z + b.w*b.w;
    #pragma unroll
    for (int off = 32; off >= 1; off >>= 1)
        sum += __shfl_down(sum, off, 64);
    if (lane == 0) *dst = sum;
}

// ------------- kernel 1: fused distance + argmax (fp32 micro-tile) ----------
// Block: 256 threads = 16 (code lanes tx) x 16 (row lanes ty).
// Each block: BN=64 rows x all 8192 codes. LDS tiles 64x64, float4 layout
// [d4][idx] with pad 65 so staging writes and ds_read_b128 are conflict-free.
// Thread tile: rows ty+16i, codes tx+16j (interleaved -> contiguous LDS reads).
__global__ __launch_bounds__(256) void dist_argmax_kernel(
    const float* __restrict__ x, const float* __restrict__ embed,
    const float* __restrict__ e_sq, const float* __restrict__ f_sq,
    int* __restrict__ out_idx)
{
    __shared__ float4 xs[16][65];
    __shared__ float4 es[16][65];

    const int t  = threadIdx.x;
    const int tx = t & 15;
    const int ty = t >> 4;
    const int row0 = blockIdx.x * BN;

    float best[4];
    int   bidx[4];
    float fs[4];
    #pragma unroll
    for (int i = 0; i < 4; ++i) {
        best[i] = -3.402823466e38f;
        bidx[i] = 0;
        fs[i]   = f_sq[row0 + ty + 16*i];
    }

    for (int cb = 0; cb < KCODES; cb += BC) {
        float acc[4][4];
        #pragma unroll
        for (int i = 0; i < 4; ++i)
            #pragma unroll
            for (int j = 0; j < 4; ++j)
                acc[i][j] = 0.f;

        for (int db = 0; db < DIM; db += BD) {
            __syncthreads();   // protect LDS from previous iteration's readers
            {
                const int rr0 = t >> 4;   // 0..15
                const int c4  = t & 15;   // 0..15  (which float4 along d)
                #pragma unroll
                for (int s = 0; s < 4; ++s) {
                    int rr = rr0 + 16*s;
                    xs[c4][rr] = *(const float4*)(x     + (size_t)(row0 + rr) * DIM + db + c4*4);
                    es[c4][rr] = *(const float4*)(embed + (size_t)(cb   + rr) * DIM + db + c4*4);
                }
            }
            __syncthreads();

            #pragma unroll
            for (int d4 = 0; d4 < 16; ++d4) {
                float4 xv[4], ev[4];
                #pragma unroll
                for (int i = 0; i < 4; ++i) xv[i] = xs[d4][ty + 16*i];
                #pragma unroll
                for (int j = 0; j < 4; ++j) ev[j] = es[d4][tx + 16*j];
                #pragma unroll
                for (int i = 0; i < 4; ++i)
                    #pragma unroll
                    for (int j = 0; j < 4; ++j) {
                        acc[i][j] += xv[i].x * ev[j].x;
                        acc[i][j] += xv[i].y * ev[j].y;
                        acc[i][j] += xv[i].z * ev[j].z;
                        acc[i][j] += xv[i].w * ev[j].w;
                    }
            }
        }

        // epilogue for this code chunk: mimic np's rounding order exactly:
        // dist = -((f_sq - 2*dot) + e_sq); first (lowest) index wins ties.
        #pragma unroll
        for (int j = 0; j < 4; ++j) {
            int c = cb + tx + 16*j;
            float esq = e_sq[c];
            #pragma unroll
            for (int i = 0; i < 4; ++i) {
                float dist = -((fs[i] - 2.0f * acc[i][j]) + esq);
                if (dist > best[i]) { best[i] = dist; bidx[i] = c; }
            }
        }
    }

    // reduce across the 16 code-lanes (contiguous lanes within one wave)
    #pragma unroll
    for (int i = 0; i < 4; ++i) {
        float b  = best[i];
        int   bi = bidx[i];
        #pragma unroll
        for (int m = 1; m < 16; m <<= 1) {
            float ob  = __shfl_xor(b,  m, 64);
            int   obi = __shfl_xor(bi, m, 64);
            if (ob > b || (ob == b && obi < bi)) { b = ob; bi = obi; }
        }
        if (tx == 0) out_idx[row0 + ty + 16*i] = bi;
    }
}

// ---------------- kernel 2: gather rows + write indices as float ------------
__global__ __launch_bounds__(256) void gather_kernel(
    const float* __restrict__ embed, const int* __restrict__ idx,
    float* __restrict__ out)
{
    int gid = blockIdx.x * 256 + threadIdx.x;   // one float4 per thread
    int row = gid >> 7;                         // 128 float4 per row
    int c4  = gid & 127;
    int k = idx[row];
    float4 v = *(const float4*)(embed + (size_t)k * DIM + (size_t)c4 * 4);
    *(float4*)(out + (size_t)row * DIM + (size_t)c4 * 4) = v;
    if (c4 == 0) out[(size_t)NROWS * DIM + row] = (float)k;
}

extern "C" void kernel_launch(void* const* d_in, const int* in_sizes, int n_in,
                              void* d_out, int out_size, void* d_ws, size_t ws_size,
                              hipStream_t stream)
{
    const float* x     = (const float*)d_in[0];   // [16384, 512]
    const float* embed = (const float*)d_in[1];   // [8192, 512]
    float* out = (float*)d_out;                   // [16384*512] quantize + [16384] idx-as-float

    float* e_sq = (float*)d_ws;                   // KCODES floats
    float* f_sq = e_sq + KCODES;                  // NROWS floats
    int*   idx  = (int*)(f_sq + NROWS);           // NROWS ints

    (void)in_sizes; (void)n_in; (void)out_size; (void)ws_size;

    const int waves = KCODES + NROWS;             // 24576 waves, 4 per block
    sqnorm_kernel<<<waves / 4, 256, 0, stream>>>(x, embed, e_sq, f_sq);
    dist_argmax_kernel<<<NROWS / BN, 256, 0, stream>>>(x, embed, e_sq, f_sq, idx);
    gather_kernel<<<(NROWS * (DIM / 4)) / 256, 256, 0, stream>>>(embed, idx, out);
}

// Round 2
// 719.584 us; speedup vs baseline: 3.8919x; 3.8919x over previous
//
#include <hip/hip_runtime.h>

#define DIM    512
#define KCODES 8192
#define NROWS  16384
#define SPLITS 4
#define CRANGE (KCODES / SPLITS)   // 2048 codes per block
#define CC     256                 // codes per chunk
#define NCHUNK (CRANGE / CC)       // 8
#define RT     128                 // rows per block
#define NEG_INF -3.402823466e38f
#define CAND_PER_ROW 64            // 4 splits * 2 wm * 4 quad * 2
#define MARGIN 0.25f

typedef unsigned short ushort_t;
typedef unsigned int uint_t;
typedef __attribute__((ext_vector_type(8))) short v8s;
typedef __attribute__((ext_vector_type(4))) float v4f;

__device__ inline ushort_t f32_to_bf16_rne(float f) {
    uint_t u = __float_as_uint(f);
    uint_t r = u + 0x7fffu + ((u >> 16) & 1u);
    return (ushort_t)(r >> 16);
}
__device__ inline float bf16_to_f32(ushort_t h) {
    return __uint_as_float(((uint_t)h) << 16);
}
__device__ inline void cvt8(float4 a, float4 b, int4& hi, int4& lo) {
    float v[8] = {a.x, a.y, a.z, a.w, b.x, b.y, b.z, b.w};
    ushort_t h[8], l[8];
    #pragma unroll
    for (int i = 0; i < 8; ++i) {
        h[i] = f32_to_bf16_rne(v[i]);
        float rem = v[i] - bf16_to_f32(h[i]);
        l[i] = f32_to_bf16_rne(rem);
    }
    hi.x = (int)((uint_t)h[0] | ((uint_t)h[1] << 16));
    hi.y = (int)((uint_t)h[2] | ((uint_t)h[3] << 16));
    hi.z = (int)((uint_t)h[4] | ((uint_t)h[5] << 16));
    hi.w = (int)((uint_t)h[6] | ((uint_t)h[7] << 16));
    lo.x = (int)((uint_t)l[0] | ((uint_t)l[1] << 16));
    lo.y = (int)((uint_t)l[2] | ((uint_t)l[3] << 16));
    lo.z = (int)((uint_t)l[4] | ((uint_t)l[5] << 16));
    lo.w = (int)((uint_t)l[6] | ((uint_t)l[7] << 16));
}

// --------- kernel 0: convert embed -> bf16 hi/lo, compute e_sq & f_sq -------
__global__ __launch_bounds__(256) void convert_kernel(
    const float* __restrict__ x, const float* __restrict__ embed,
    ushort_t* __restrict__ e_hi, ushort_t* __restrict__ e_lo,
    float* __restrict__ e_sq, float* __restrict__ f_sq)
{
    int g = blockIdx.x * 4 + (threadIdx.x >> 6);
    int lane = threadIdx.x & 63;
    if (g < KCODES) {
        const float4* src = (const float4*)(embed + (size_t)g * DIM + lane * 8);
        float4 a = src[0], b = src[1];
        int4 hi, lo;
        cvt8(a, b, hi, lo);
        *(int4*)(e_hi + (size_t)g * DIM + lane * 8) = hi;
        *(int4*)(e_lo + (size_t)g * DIM + lane * 8) = lo;
        float s = a.x*a.x + a.y*a.y + a.z*a.z + a.w*a.w
                + b.x*b.x + b.y*b.y + b.z*b.z + b.w*b.w;
        #pragma unroll
        for (int off = 32; off >= 1; off >>= 1) s += __shfl_down(s, off, 64);
        if (lane == 0) e_sq[g] = s;
    } else {
        int r = g - KCODES;
        const float4* src = (const float4*)(x + (size_t)r * DIM + lane * 8);
        float4 a = src[0], b = src[1];
        float s = a.x*a.x + a.y*a.y + a.z*a.z + a.w*a.w
                + b.x*b.x + b.y*b.y + b.z*b.z + b.w*b.w;
        #pragma unroll
        for (int off = 32; off >= 1; off >>= 1) s += __shfl_down(s, off, 64);
        if (lane == 0) f_sq[r] = s;
    }
}

// --------- kernel 1: bf16 hi/lo MFMA screening GEMM + per-subset top-2 ------
// Grid: 512 blocks = 128 row-tiles x 4 code-splits. Block: 256 thr = 4 waves
// (wm,wn in 2x2). Wave tile: 128 codes x 64 rows of 16x16x32 bf16 MFMA frags.
// score = 2*dot - e_sq; per-(lane,nj) running top-2 over its disjoint subset.
__global__ __launch_bounds__(256, 2) void screen_kernel(
    const float* __restrict__ x,
    const ushort_t* __restrict__ e_hi, const ushort_t* __restrict__ e_lo,
    const float* __restrict__ e_sq,
    float* __restrict__ cand_s, int* __restrict__ cand_i)
{
    __shared__ __align__(16) short EH[4][CC][8];
    __shared__ __align__(16) short EL[4][CC][8];
    __shared__ __align__(16) short XH[4][RT][8];
    __shared__ __align__(16) short XL[4][RT][8];
    __shared__ float esq_s[CC];

    const int t = threadIdx.x;
    const int split = blockIdx.x & 3;
    const int row0 = (blockIdx.x >> 2) * RT;
    const int cbase = split * CRANGE;

    const int w = t >> 6;
    const int wm = w & 1;        // code half of the chunk
    const int wn = w >> 1;       // row half of the block
    const int lane = t & 63;
    const int quad = lane >> 4;
    const int l15 = lane & 15;

    float b1[4], b2[4];
    int   i1[4], i2[4];
    #pragma unroll
    for (int nj = 0; nj < 4; ++nj) { b1[nj] = NEG_INF; b2[nj] = NEG_INF; i1[nj] = 0; i2[nj] = 0; }

    const int xr   = t & 127;         // x staging row
    const int kp   = (t >> 7) * 2;    // x staging kseg pair

    for (int chunk = 0; chunk < NCHUNK; ++chunk) {
        const int cchunk = cbase + chunk * CC;
        __syncthreads();
        esq_s[t] = e_sq[cchunk + t];

        v4f acc[8][4];
        #pragma unroll
        for (int mi = 0; mi < 8; ++mi)
            #pragma unroll
            for (int nj = 0; nj < 4; ++nj)
                acc[mi][nj] = (v4f){0.f, 0.f, 0.f, 0.f};

        for (int ks = 0; ks < 16; ++ks) {
            const int k0 = ks * 32;
            __syncthreads();
            // stage E: thread t owns code-row t's 64B k-slab (bf16 source)
            {
                const int4* sh = (const int4*)(e_hi + (size_t)(cchunk + t) * DIM + k0);
                const int4* sl = (const int4*)(e_lo + (size_t)(cchunk + t) * DIM + k0);
                #pragma unroll
                for (int q = 0; q < 4; ++q) {
                    *(int4*)(&EH[q][t][0]) = sh[q];
                    *(int4*)(&EL[q][t][0]) = sl[q];
                }
            }
            // stage X: convert fp32 -> bf16 hi/lo on the fly
            {
                const float4* xs = (const float4*)(x + (size_t)(row0 + xr) * DIM + k0 + kp * 8);
                #pragma unroll
                for (int q = 0; q < 2; ++q) {
                    float4 a = xs[2*q], b = xs[2*q + 1];
                    int4 hi, lo;
                    cvt8(a, b, hi, lo);
                    *(int4*)(&XH[kp + q][xr][0]) = hi;
                    *(int4*)(&XL[kp + q][xr][0]) = lo;
                }
            }
            __syncthreads();

            v8s bh[4], bl[4];
            #pragma unroll
            for (int nj = 0; nj < 4; ++nj) {
                int br = wn * 64 + nj * 16 + l15;
                bh[nj] = *(const v8s*)(&XH[quad][br][0]);
                bl[nj] = *(const v8s*)(&XL[quad][br][0]);
            }
            #pragma unroll
            for (int mi = 0; mi < 8; ++mi) {
                int ar = wm * 128 + mi * 16 + l15;
                v8s ah = *(const v8s*)(&EH[quad][ar][0]);
                v8s al = *(const v8s*)(&EL[quad][ar][0]);
                #pragma unroll
                for (int nj = 0; nj < 4; ++nj) {
                    acc[mi][nj] = __builtin_amdgcn_mfma_f32_16x16x32_bf16(ah, bh[nj], acc[mi][nj], 0, 0, 0);
                    acc[mi][nj] = __builtin_amdgcn_mfma_f32_16x16x32_bf16(ah, bl[nj], acc[mi][nj], 0, 0, 0);
                    acc[mi][nj] = __builtin_amdgcn_mfma_f32_16x16x32_bf16(al, bh[nj], acc[mi][nj], 0, 0, 0);
                }
            }
        }

        // epilogue: per-lane stream is index-ascending (chunk asc, mi asc, r asc)
        #pragma unroll
        for (int mi = 0; mi < 8; ++mi) {
            int cloc = wm * 128 + mi * 16 + quad * 4;
            #pragma unroll
            for (int r = 0; r < 4; ++r) {
                float esq = esq_s[cloc + r];
                int cg = cchunk + cloc + r;
                #pragma unroll
                for (int nj = 0; nj < 4; ++nj) {
                    float s = 2.0f * acc[mi][nj][r] - esq;
                    if (s > b2[nj]) {
                        if (s > b1[nj]) { b2[nj] = b1[nj]; i2[nj] = i1[nj]; b1[nj] = s; i1[nj] = cg; }
                        else            { b2[nj] = s;      i2[nj] = cg; }
                    }
                }
            }
        }
    }

    // write candidates: 2 per (lane, nj); disjoint slots per row
    #pragma unroll
    for (int nj = 0; nj < 4; ++nj) {
        int row = row0 + wn * 64 + nj * 16 + l15;
        int slot = split * 16 + wm * 8 + quad * 2;
        size_t b = (size_t)row * CAND_PER_ROW + slot;
        cand_s[b]     = b1[nj];  cand_i[b]     = i1[nj];
        cand_s[b + 1] = b2[nj];  cand_i[b + 1] = i2[nj];
    }
}

// --------- kernel 2: exact fp32 rescore of margin-filtered candidates -------
__global__ __launch_bounds__(256) void rescore_kernel(
    const float* __restrict__ x, const float* __restrict__ embed,
    const float* __restrict__ e_sq, const float* __restrict__ f_sq,
    const float* __restrict__ cand_s, const int* __restrict__ cand_i,
    float* __restrict__ out)
{
    int row = blockIdx.x * 4 + (threadIdx.x >> 6);
    int lane = threadIdx.x & 63;

    float cs = cand_s[(size_t)row * CAND_PER_ROW + lane];
    int   ci = cand_i[(size_t)row * CAND_PER_ROW + lane];

    float m = cs;
    #pragma unroll
    for (int o = 32; o >= 1; o >>= 1) m = fmaxf(m, __shfl_xor(m, o, 64));

    unsigned long long mask = __ballot(cs >= m - MARGIN);

    const float4* xsrc = (const float4*)(x + (size_t)row * DIM + lane * 8);
    float4 xa = xsrc[0], xb = xsrc[1];
    float fsq = f_sq[row];

    float bd = NEG_INF;
    int   bi = 0x7fffffff;

    while (mask) {
        int p = __ffsll(mask) - 1;
        mask &= mask - 1;
        int c = __shfl(ci, p);
        const float4* er = (const float4*)(embed + (size_t)c * DIM + lane * 8);
        float4 ea = er[0], eb = er[1];
        float part = xa.x*ea.x + xa.y*ea.y + xa.z*ea.z + xa.w*ea.w
                   + xb.x*eb.x + xb.y*eb.y + xb.z*eb.z + xb.w*eb.w;
        #pragma unroll
        for (int o = 32; o >= 1; o >>= 1) part += __shfl_xor(part, o, 64);
        float d = -((fsq - 2.0f * part) + e_sq[c]);
        if (d > bd || (d == bd && c < bi)) { bd = d; bi = c; }
    }

    const float4* er = (const float4*)(embed + (size_t)bi * DIM + lane * 8);
    float4 qa = er[0], qb = er[1];
    float4* dst = (float4*)(out + (size_t)row * DIM + lane * 8);
    dst[0] = qa; dst[1] = qb;
    if (lane == 0) out[(size_t)NROWS * DIM + row] = (float)bi;
}

extern "C" void kernel_launch(void* const* d_in, const int* in_sizes, int n_in,
                              void* d_out, int out_size, void* d_ws, size_t ws_size,
                              hipStream_t stream)
{
    const float* x     = (const float*)d_in[0];   // [16384, 512]
    const float* embed = (const float*)d_in[1];   // [8192, 512]
    float* out = (float*)d_out;

    float* e_sq   = (float*)d_ws;                              // 8192
    float* f_sq   = e_sq + KCODES;                             // 16384
    float* cand_s = f_sq + NROWS;                              // 16384*64
    int*   cand_i = (int*)(cand_s + (size_t)NROWS * CAND_PER_ROW);
    ushort_t* e_hi = (ushort_t*)(cand_i + (size_t)NROWS * CAND_PER_ROW);
    ushort_t* e_lo = e_hi + (size_t)KCODES * DIM;
    // total ws use: ~25.3 MB

    (void)in_sizes; (void)n_in; (void)out_size; (void)ws_size;

    convert_kernel<<<(KCODES + NROWS) / 4, 256, 0, stream>>>(x, embed, e_hi, e_lo, e_sq, f_sq);
    screen_kernel<<<(NROWS / RT) * SPLITS, 256, 0, stream>>>(x, e_hi, e_lo, e_sq, cand_s, cand_i);
    rescore_kernel<<<NROWS / 4, 256, 0, stream>>>(x, embed, e_sq, f_sq, cand_s, cand_i, out);
}